// Round 1
// baseline (3618.711 us; speedup 1.0000x reference)
//
#include <hip/hip_runtime.h>
#include <hip/hip_bf16.h>
#include <math.h>

#define B_ 16
#define T_ 512
#define C_ 1024
#define H_ 16
#define D_ 64
#define F_ 4096
#define L_ 8
#define M_ (B_*T_)   // 8192 rows

typedef __hip_bfloat16 bf16;
typedef __attribute__((ext_vector_type(8))) short short8;
typedef __attribute__((ext_vector_type(4))) float f32x4;

__device__ __forceinline__ short f2bs(float x){
  union { __hip_bfloat16 h; short s; } u;
  u.h = __float2bfloat16(x);
  return u.s;
}

__device__ __forceinline__ void gload16(const void* g, void* l){
  __builtin_amdgcn_global_load_lds((const __attribute__((address_space(1))) void*)g,
      (__attribute__((address_space(3))) void*)l, 16, 0, 0);
}

// ---------------- weight transpose+convert: W[K,N] f32 -> Wt[N,K] bf16 ----------------
__global__ __launch_bounds__(256) void convert_w(
    const float* __restrict__ Wq, const float* __restrict__ Wk,
    const float* __restrict__ Wv, const float* __restrict__ Wo,
    const float* __restrict__ W1, const float* __restrict__ W2,
    bf16* __restrict__ slab)
{
  __shared__ float t[32][33];
  int bid = blockIdx.x;
  const float* src; bf16* dst; int K, N, tile;
  if (bid < 4096) {
    int m = bid >> 10;
    src = (m==0)?Wq:(m==1)?Wk:(m==2)?Wv:Wo;
    dst = slab + (size_t)m*C_*C_;
    K = C_; N = C_; tile = bid & 1023;
  } else if (bid < 8192) {
    src = W1; dst = slab + (size_t)4*C_*C_; K = C_; N = F_; tile = bid - 4096;
  } else {
    src = W2; dst = slab + (size_t)4*C_*C_ + (size_t)C_*F_; K = F_; N = C_; tile = bid - 8192;
  }
  int tilesN = N >> 5;
  int tk = tile / tilesN, tn = tile % tilesN;
  int r = threadIdx.x >> 5, c = threadIdx.x & 31;
  #pragma unroll
  for (int i=0;i<4;i++)
    t[r + i*8][c] = src[(size_t)(tk*32 + r + i*8)*N + tn*32 + c];
  __syncthreads();
  #pragma unroll
  for (int i=0;i<4;i++)
    dst[(size_t)(tn*32 + r + i*8)*K + tk*32 + c] = __float2bfloat16(t[c][r + i*8]);
}

// ---------------- LayerNorm: f32 [M,C] -> bf16 [M,C] ----------------
__global__ __launch_bounds__(256) void ln_k(const float* __restrict__ in,
    const float* __restrict__ g, const float* __restrict__ be, bf16* __restrict__ out)
{
  int row = blockIdx.x;
  int tid = threadIdx.x;
  int w = tid >> 6, lane = tid & 63;
  float4 v = reinterpret_cast<const float4*>(in + (size_t)row*C_)[tid];
  float s = v.x+v.y+v.z+v.w;
  float ss = v.x*v.x+v.y*v.y+v.z*v.z+v.w*v.w;
  #pragma unroll
  for (int o=32;o>=1;o>>=1){ s += __shfl_xor(s,o); ss += __shfl_xor(ss,o); }
  __shared__ float sa[4], sb[4];
  if (lane==0){ sa[w]=s; sb[w]=ss; }
  __syncthreads();
  s  = sa[0]+sa[1]+sa[2]+sa[3];
  ss = sb[0]+sb[1]+sb[2]+sb[3];
  float mean = s * (1.0f/C_);
  float var  = ss * (1.0f/C_) - mean*mean;
  float rs = rsqrtf(var + 1e-5f);
  float4 gv = reinterpret_cast<const float4*>(g)[tid];
  float4 bv = reinterpret_cast<const float4*>(be)[tid];
  ushort4 o;
  o.x = (unsigned short)f2bs((v.x-mean)*rs*gv.x + bv.x);
  o.y = (unsigned short)f2bs((v.y-mean)*rs*gv.y + bv.y);
  o.z = (unsigned short)f2bs((v.z-mean)*rs*gv.z + bv.z);
  o.w = (unsigned short)f2bs((v.w-mean)*rs*gv.w + bv.w);
  reinterpret_cast<ushort4*>(out + (size_t)row*C_)[tid] = o;
}

// ---------------- GEMM: out[M,N] = A[M,K](bf16) @ Wt^T (Wt[N,K] bf16) + bias ----------------
// EPI: 0 = bf16 store, 1 = exact-GELU bf16 store, 2 = fp32 residual accumulate
template<int EPI>
__global__ __launch_bounds__(256) void gemm_k(const bf16* __restrict__ A,
    const bf16* __restrict__ Bt, const float* __restrict__ bias,
    void* __restrict__ outp, int N, int K)
{
  __shared__ bf16 As[2][128*32];
  __shared__ bf16 Bs[2][128*32];
  int tid = threadIdx.x, lane = tid&63, w = tid>>6;
  int wr = w>>1, wc = w&1;
  int R0 = blockIdx.y*128, C0 = blockIdx.x*128;
  const f32x4 fz = {0.f,0.f,0.f,0.f};
  f32x4 acc[4][4];
  #pragma unroll
  for (int m=0;m<4;m++)
    #pragma unroll
    for (int n=0;n<4;n++) acc[m][n] = fz;

  const int KT = K >> 5;
  auto stage = [&](int buf, int kt){
    #pragma unroll
    for (int is=0; is<2; ++is){
      int cc = is*256 + tid;
      int row = cc>>2, ch = cc&3;
      gload16(A  + (size_t)(R0+row)*K + kt*32 + ch*8, &As[buf][cc*8]);
      gload16(Bt + (size_t)(C0+row)*K + kt*32 + ch*8, &Bs[buf][cc*8]);
    }
  };
  stage(0,0);
  int cur = 0;
  for (int kt=0; kt<KT; ++kt){
    __syncthreads();
    if (kt+1 < KT) stage(cur^1, kt+1);
    short8 af[4], bfr[4];
    #pragma unroll
    for (int m=0;m<4;m++)
      af[m] = *reinterpret_cast<const short8*>(&As[cur][(wr*64 + m*16 + (lane&15))*32 + (lane>>4)*8]);
    #pragma unroll
    for (int n=0;n<4;n++)
      bfr[n] = *reinterpret_cast<const short8*>(&Bs[cur][(wc*64 + n*16 + (lane&15))*32 + (lane>>4)*8]);
    #pragma unroll
    for (int m=0;m<4;m++)
      #pragma unroll
      for (int n=0;n<4;n++)
        acc[m][n] = __builtin_amdgcn_mfma_f32_16x16x32_bf16(af[m], bfr[n], acc[m][n], 0,0,0);
    cur ^= 1;
  }
  #pragma unroll
  for (int m=0;m<4;m++){
    #pragma unroll
    for (int n=0;n<4;n++){
      int col = C0 + wc*64 + n*16 + (lane&15);
      float bb = bias[col];
      #pragma unroll
      for (int r=0;r<4;r++){
        int row = R0 + wr*64 + m*16 + (lane>>4)*4 + r;
        float vv = acc[m][n][r] + bb;
        if (EPI==0){
          ((bf16*)outp)[(size_t)row*N + col] = __float2bfloat16(vv);
        } else if (EPI==1){
          float gl = 0.5f*vv*(1.0f + erff(vv*0.70710678118654752f));
          ((bf16*)outp)[(size_t)row*N + col] = __float2bfloat16(gl);
        } else {
          ((float*)outp)[(size_t)row*N + col] += vv;
        }
      }
    }
  }
}

// ---------------- Flash attention, non-causal, per (b,h); K,V fully in LDS ----------------
__global__ __launch_bounds__(512) void attn_k(const bf16* __restrict__ q,
    const bf16* __restrict__ k, const bf16* __restrict__ v, bf16* __restrict__ y)
{
  __shared__ bf16 Ks[T_*64];   // 64 KB, XOR-swizzled rows
  __shared__ bf16 Vs[T_*64];   // 64 KB, shifted-slot rows
  int tid = threadIdx.x, lane = tid&63, w = tid>>6;
  int b = blockIdx.z, h = blockIdx.y, qt = blockIdx.x;
  size_t base = ((size_t)b*T_)*C_ + (size_t)h*64;

  #pragma unroll
  for (int i=0;i<8;i++){
    int cc = i*512 + tid;
    int row = cc>>3, ch = cc&7;
    short8 kv = *reinterpret_cast<const short8*>(k + base + (size_t)row*C_ + ch*8);
    short8 vv = *reinterpret_cast<const short8*>(v + base + (size_t)row*C_ + ch*8);
    int mk = (row&7) ^ (((row>>3)&3)<<1);
    int slotK = ch ^ mk;
    int slotV = (ch + 2*((row>>3)&3)) & 7;
    *reinterpret_cast<short8*>((char*)Ks + row*128 + slotK*16) = kv;
    *reinterpret_cast<short8*>((char*)Vs + row*128 + slotV*16) = vv;
  }
  __syncthreads();

  int g = lane>>4, r16 = lane&15;
  int qrow0 = qt*256 + w*32;
  short8 qf[2][2];
  #pragma unroll
  for (int s=0;s<2;s++)
    #pragma unroll
    for (int c=0;c<2;c++)
      qf[s][c] = *reinterpret_cast<const short8*>(q + base + (size_t)(qrow0 + s*16 + r16)*C_ + c*32 + g*8);

  const f32x4 fz = {0.f,0.f,0.f,0.f};
  float mreg[2] = {-1e30f, -1e30f};
  float lsum[2] = {0.f, 0.f};
  f32x4 yacc[2][4];
  #pragma unroll
  for (int s=0;s<2;s++)
    #pragma unroll
    for (int dt=0;dt<4;dt++) yacc[s][dt] = fz;

  const float SC = 0.18033688011112043f; // (1/sqrt(64)) * log2(e)
  int rl0 = ((r16>>2)<<3) + (r16&3);     // k-row permutation so PV B-frag is lane-local

  for (int kt=0; kt<16; ++kt){
    int rowA = kt*32 + rl0;
    int rowB = rowA + 4;
    short8 kf0[2], kf1[2];
    #pragma unroll
    for (int c=0;c<2;c++){
      int slot = c*4 + g;
      int mkA = (rowA&7) ^ (((rowA>>3)&3)<<1);
      int mkB = (rowB&7) ^ (((rowB>>3)&3)<<1);
      kf0[c] = *reinterpret_cast<const short8*>((char*)Ks + rowA*128 + (slot^mkA)*16);
      kf1[c] = *reinterpret_cast<const short8*>((char*)Ks + rowB*128 + (slot^mkB)*16);
    }
    short8 vf[4];
    #pragma unroll
    for (int dt=0; dt<4; dt++){
      #pragma unroll
      for (int j=0;j<8;j++){
        int row = kt*32 + g*8 + j;
        int col = dt*16 + r16;
        int slot = ((col>>3) + 2*((row>>3)&3)) & 7;
        vf[dt][j] = *reinterpret_cast<const short*>((char*)Vs + row*128 + slot*16 + (col&7)*2);
      }
    }
    short8 pf[2];
    #pragma unroll
    for (int s=0;s<2;s++){
      f32x4 st0 = fz, st1 = fz;
      st0 = __builtin_amdgcn_mfma_f32_16x16x32_bf16(kf0[0], qf[s][0], st0, 0,0,0);
      st0 = __builtin_amdgcn_mfma_f32_16x16x32_bf16(kf0[1], qf[s][1], st0, 0,0,0);
      st1 = __builtin_amdgcn_mfma_f32_16x16x32_bf16(kf1[0], qf[s][0], st1, 0,0,0);
      st1 = __builtin_amdgcn_mfma_f32_16x16x32_bf16(kf1[1], qf[s][1], st1, 0,0,0);
      float p0[4], p1[4];
      float tm = -1e30f;
      #pragma unroll
      for (int r=0;r<4;r++){
        p0[r] = st0[r]*SC; p1[r] = st1[r]*SC;
        tm = fmaxf(tm, fmaxf(p0[r], p1[r]));
      }
      tm = fmaxf(tm, __shfl_xor(tm, 16));
      tm = fmaxf(tm, __shfl_xor(tm, 32));
      float nm = fmaxf(mreg[s], tm);
      float f = exp2f(mreg[s] - nm);
      mreg[s] = nm;
      float psum = 0.f;
      #pragma unroll
      for (int r=0;r<4;r++){
        p0[r] = exp2f(p0[r]-nm); p1[r] = exp2f(p1[r]-nm);
        psum += p0[r] + p1[r];
      }
      lsum[s] = lsum[s]*f + psum;
      #pragma unroll
      for (int dt=0;dt<4;dt++) yacc[s][dt] *= f;
      short8 pp;
      pp[0]=f2bs(p0[0]); pp[1]=f2bs(p0[1]); pp[2]=f2bs(p0[2]); pp[3]=f2bs(p0[3]);
      pp[4]=f2bs(p1[0]); pp[5]=f2bs(p1[1]); pp[6]=f2bs(p1[2]); pp[7]=f2bs(p1[3]);
      pf[s] = pp;
    }
    #pragma unroll
    for (int dt=0;dt<4;dt++){
      yacc[0][dt] = __builtin_amdgcn_mfma_f32_16x16x32_bf16(vf[dt], pf[0], yacc[0][dt], 0,0,0);
      yacc[1][dt] = __builtin_amdgcn_mfma_f32_16x16x32_bf16(vf[dt], pf[1], yacc[1][dt], 0,0,0);
    }
  }

  #pragma unroll
  for (int s=0;s<2;s++){
    float ls = lsum[s];
    ls += __shfl_xor(ls, 16);
    ls += __shfl_xor(ls, 32);
    float inv = 1.0f/ls;
    int qrow = qrow0 + s*16 + r16;
    #pragma unroll
    for (int dt=0;dt<4;dt++){
      ushort4 o;
      o.x = (unsigned short)f2bs(yacc[s][dt][0]*inv);
      o.y = (unsigned short)f2bs(yacc[s][dt][1]*inv);
      o.z = (unsigned short)f2bs(yacc[s][dt][2]*inv);
      o.w = (unsigned short)f2bs(yacc[s][dt][3]*inv);
      *reinterpret_cast<ushort4*>(y + base + (size_t)qrow*C_ + dt*16 + g*4) = o;
    }
  }
}

// ---------------- final LN (last token only) + pooling head ----------------
__global__ __launch_bounds__(256) void head_k(const float* __restrict__ hbuf,
    const float* __restrict__ gf, const float* __restrict__ bfv,
    const float* __restrict__ Wp, const float* __restrict__ bp, float* __restrict__ out)
{
  int b = blockIdx.x, tid = threadIdx.x;
  int w = tid >> 6, lane = tid & 63;
  const float* rowp = hbuf + ((size_t)(b*T_ + T_-1))*C_;
  float4 v = reinterpret_cast<const float4*>(rowp)[tid];
  float s = v.x+v.y+v.z+v.w;
  float ss = v.x*v.x+v.y*v.y+v.z*v.z+v.w*v.w;
  #pragma unroll
  for (int o=32;o>=1;o>>=1){ s += __shfl_xor(s,o); ss += __shfl_xor(ss,o); }
  __shared__ float sa[4], sb[4];
  if (lane==0){ sa[w]=s; sb[w]=ss; }
  __syncthreads();
  s  = sa[0]+sa[1]+sa[2]+sa[3];
  ss = sb[0]+sb[1]+sb[2]+sb[3];
  float mean = s * (1.0f/C_);
  float var  = ss * (1.0f/C_) - mean*mean;
  float rs = rsqrtf(var + 1e-5f);
  __shared__ float nrm[C_];
  float4 gv = reinterpret_cast<const float4*>(gf)[tid];
  float4 bv = reinterpret_cast<const float4*>(bfv)[tid];
  nrm[tid*4+0] = (v.x-mean)*rs*gv.x + bv.x;
  nrm[tid*4+1] = (v.y-mean)*rs*gv.y + bv.y;
  nrm[tid*4+2] = (v.z-mean)*rs*gv.z + bv.z;
  nrm[tid*4+3] = (v.w-mean)*rs*gv.w + bv.w;
  __syncthreads();
  float acc = bp[tid];
  #pragma unroll 4
  for (int kk=0; kk<C_; kk++) acc += nrm[kk]*Wp[(size_t)kk*256 + tid];
  out[b*256 + tid] = acc;
}

extern "C" void kernel_launch(void* const* d_in, const int* in_sizes, int n_in,
                              void* d_out, int out_size, void* d_ws, size_t ws_size,
                              hipStream_t stream)
{
  const float* x  = (const float*)d_in[0];
  const float* Wq = (const float*)d_in[1];
  const float* bq = (const float*)d_in[2];
  const float* Wk = (const float*)d_in[3];
  const float* bk = (const float*)d_in[4];
  const float* Wv = (const float*)d_in[5];
  const float* bv = (const float*)d_in[6];
  const float* Wo = (const float*)d_in[7];
  const float* bo = (const float*)d_in[8];
  const float* g1 = (const float*)d_in[9];
  const float* be1= (const float*)d_in[10];
  const float* g2 = (const float*)d_in[11];
  const float* be2= (const float*)d_in[12];
  const float* W1 = (const float*)d_in[13];
  const float* b1 = (const float*)d_in[14];
  const float* W2 = (const float*)d_in[15];
  const float* b2 = (const float*)d_in[16];
  const float* gf = (const float*)d_in[17];
  const float* bfv= (const float*)d_in[18];
  const float* Wp = (const float*)d_in[19];
  const float* bp = (const float*)d_in[20];
  float* out = (float*)d_out;

  const size_t NEED = 209715200;
  if (ws_size < NEED) return;

  char* ws = (char*)d_ws;
  float* hbuf = (float*)ws;                      // 33,554,432 B (fp32 residual)
  bf16* abuf  = (bf16*)(ws + 33554432);          // 16,777,216 B
  bf16* qbuf  = (bf16*)(ws + 50331648);
  bf16* kbuf  = (bf16*)(ws + 67108864);
  bf16* vbuf  = (bf16*)(ws + 83886080);
  bf16* ybuf  = (bf16*)(ws + 100663296);
  bf16* mid   = (bf16*)(ws + 117440512);         // 67,108,864 B
  bf16* slab  = (bf16*)(ws + 184549376);         // 25,165,824 B (per-layer bf16 weights, transposed)

  hipMemcpyAsync(hbuf, x, (size_t)M_*C_*sizeof(float), hipMemcpyDeviceToDevice, stream);

  dim3 gN1024(8, 64), gN4096(32, 64);
  for (int l=0; l<L_; ++l){
    size_t oCC = (size_t)l*C_*C_, oC = (size_t)l*C_;
    size_t oCF = (size_t)l*C_*F_, oF = (size_t)l*F_;
    convert_w<<<12288, 256, 0, stream>>>(Wq+oCC, Wk+oCC, Wv+oCC, Wo+oCC, W1+oCF, W2+oCF, slab);
    ln_k<<<M_, 256, 0, stream>>>(hbuf, g1+oC, be1+oC, abuf);
    gemm_k<0><<<gN1024, 256, 0, stream>>>(abuf, slab,                      bq+oC, qbuf, C_, C_);
    gemm_k<0><<<gN1024, 256, 0, stream>>>(abuf, slab + (size_t)1*C_*C_,    bk+oC, kbuf, C_, C_);
    gemm_k<0><<<gN1024, 256, 0, stream>>>(abuf, slab + (size_t)2*C_*C_,    bv+oC, vbuf, C_, C_);
    attn_k<<<dim3(2, H_, B_), 512, 0, stream>>>(qbuf, kbuf, vbuf, ybuf);
    gemm_k<2><<<gN1024, 256, 0, stream>>>(ybuf, slab + (size_t)3*C_*C_,    bo+oC, hbuf, C_, C_);
    ln_k<<<M_, 256, 0, stream>>>(hbuf, g2+oC, be2+oC, abuf);
    gemm_k<1><<<gN4096, 256, 0, stream>>>(abuf, slab + (size_t)4*C_*C_,    b1+oF, mid, F_, C_);
    gemm_k<2><<<gN1024, 256, 0, stream>>>(mid, slab + (size_t)4*C_*C_ + (size_t)C_*F_, b2+oC, hbuf, C_, F_);
  }
  head_k<<<B_, 256, 0, stream>>>(hbuf, gf, bfv, Wp, bp, out);
}

// Round 2
// 3384.390 us; speedup vs baseline: 1.0692x; 1.0692x over previous
//
#include <hip/hip_runtime.h>
#include <hip/hip_bf16.h>
#include <math.h>

#define B_ 16
#define T_ 512
#define C_ 1024
#define H_ 16
#define D_ 64
#define F_ 4096
#define L_ 8
#define M_ (B_*T_)   // 8192 rows

typedef __hip_bfloat16 bf16;
typedef __attribute__((ext_vector_type(8))) short short8;
typedef __attribute__((ext_vector_type(4))) float f32x4;

__device__ __forceinline__ short f2bs(float x){
  union { __hip_bfloat16 h; short s; } u;
  u.h = __float2bfloat16(x);
  return u.s;
}

__device__ __forceinline__ void gload16(const void* g, void* l){
  __builtin_amdgcn_global_load_lds((const __attribute__((address_space(1))) void*)g,
      (__attribute__((address_space(3))) void*)l, 16, 0, 0);
}

// ---------------- weight transpose+convert: W[K,N] f32 -> Wt[N,K] bf16 ----------------
__global__ __launch_bounds__(256) void convert_w(
    const float* __restrict__ Wq, const float* __restrict__ Wk,
    const float* __restrict__ Wv, const float* __restrict__ Wo,
    const float* __restrict__ W1, const float* __restrict__ W2,
    bf16* __restrict__ slab)
{
  __shared__ float t[32][33];
  int bid = blockIdx.x;
  const float* src; bf16* dst; int K, N, tile;
  if (bid < 4096) {
    int m = bid >> 10;
    src = (m==0)?Wq:(m==1)?Wk:(m==2)?Wv:Wo;
    dst = slab + (size_t)m*C_*C_;
    K = C_; N = C_; tile = bid & 1023;
  } else if (bid < 8192) {
    src = W1; dst = slab + (size_t)4*C_*C_; K = C_; N = F_; tile = bid - 4096;
  } else {
    src = W2; dst = slab + (size_t)4*C_*C_ + (size_t)C_*F_; K = F_; N = C_; tile = bid - 8192;
  }
  int tilesN = N >> 5;
  int tk = tile / tilesN, tn = tile % tilesN;
  int r = threadIdx.x >> 5, c = threadIdx.x & 31;
  #pragma unroll
  for (int i=0;i<4;i++)
    t[r + i*8][c] = src[(size_t)(tk*32 + r + i*8)*N + tn*32 + c];
  __syncthreads();
  #pragma unroll
  for (int i=0;i<4;i++)
    dst[(size_t)(tn*32 + r + i*8)*K + tk*32 + c] = __float2bfloat16(t[c][r + i*8]);
}

// ---------------- LayerNorm: f32 [M,C] -> bf16 [M,C] ----------------
__global__ __launch_bounds__(256) void ln_k(const float* __restrict__ in,
    const float* __restrict__ g, const float* __restrict__ be, bf16* __restrict__ out)
{
  int row = blockIdx.x;
  int tid = threadIdx.x;
  int w = tid >> 6, lane = tid & 63;
  float4 v = reinterpret_cast<const float4*>(in + (size_t)row*C_)[tid];
  float s = v.x+v.y+v.z+v.w;
  float ss = v.x*v.x+v.y*v.y+v.z*v.z+v.w*v.w;
  #pragma unroll
  for (int o=32;o>=1;o>>=1){ s += __shfl_xor(s,o); ss += __shfl_xor(ss,o); }
  __shared__ float sa[4], sb[4];
  if (lane==0){ sa[w]=s; sb[w]=ss; }
  __syncthreads();
  s  = sa[0]+sa[1]+sa[2]+sa[3];
  ss = sb[0]+sb[1]+sb[2]+sb[3];
  float mean = s * (1.0f/C_);
  float var  = ss * (1.0f/C_) - mean*mean;
  float rs = rsqrtf(var + 1e-5f);
  float4 gv = reinterpret_cast<const float4*>(g)[tid];
  float4 bv = reinterpret_cast<const float4*>(be)[tid];
  ushort4 o;
  o.x = (unsigned short)f2bs((v.x-mean)*rs*gv.x + bv.x);
  o.y = (unsigned short)f2bs((v.y-mean)*rs*gv.y + bv.y);
  o.z = (unsigned short)f2bs((v.z-mean)*rs*gv.z + bv.z);
  o.w = (unsigned short)f2bs((v.w-mean)*rs*gv.w + bv.w);
  reinterpret_cast<ushort4*>(out + (size_t)row*C_)[tid] = o;
}

// ---------------- legacy 128x128 GEMM (kept for Wo): out += A @ Bt^T + bias ----------------
template<int EPI>
__global__ __launch_bounds__(256) void gemm_k(const bf16* __restrict__ A,
    const bf16* __restrict__ Bt, const float* __restrict__ bias,
    void* __restrict__ outp, int N, int K)
{
  __shared__ bf16 As[2][128*32];
  __shared__ bf16 Bs[2][128*32];
  int tid = threadIdx.x, lane = tid&63, w = tid>>6;
  int wr = w>>1, wc = w&1;
  int R0 = blockIdx.y*128, C0 = blockIdx.x*128;
  const f32x4 fz = {0.f,0.f,0.f,0.f};
  f32x4 acc[4][4];
  #pragma unroll
  for (int m=0;m<4;m++)
    #pragma unroll
    for (int n=0;n<4;n++) acc[m][n] = fz;

  const int KT = K >> 5;
  auto stage = [&](int buf, int kt){
    #pragma unroll
    for (int is=0; is<2; ++is){
      int cc = is*256 + tid;
      int row = cc>>2, ch = cc&3;
      gload16(A  + (size_t)(R0+row)*K + kt*32 + ch*8, &As[buf][cc*8]);
      gload16(Bt + (size_t)(C0+row)*K + kt*32 + ch*8, &Bs[buf][cc*8]);
    }
  };
  stage(0,0);
  int cur = 0;
  for (int kt=0; kt<KT; ++kt){
    __syncthreads();
    if (kt+1 < KT) stage(cur^1, kt+1);
    short8 af[4], bfr[4];
    #pragma unroll
    for (int m=0;m<4;m++)
      af[m] = *reinterpret_cast<const short8*>(&As[cur][(wr*64 + m*16 + (lane&15))*32 + (lane>>4)*8]);
    #pragma unroll
    for (int n=0;n<4;n++)
      bfr[n] = *reinterpret_cast<const short8*>(&Bs[cur][(wc*64 + n*16 + (lane&15))*32 + (lane>>4)*8]);
    #pragma unroll
    for (int m=0;m<4;m++)
      #pragma unroll
      for (int n=0;n<4;n++)
        acc[m][n] = __builtin_amdgcn_mfma_f32_16x16x32_bf16(af[m], bfr[n], acc[m][n], 0,0,0);
    cur ^= 1;
  }
  #pragma unroll
  for (int m=0;m<4;m++){
    #pragma unroll
    for (int n=0;n<4;n++){
      int col = C0 + wc*64 + n*16 + (lane&15);
      float bb = bias[col];
      #pragma unroll
      for (int r=0;r<4;r++){
        int row = R0 + wr*64 + m*16 + (lane>>4)*4 + r;
        float vv = acc[m][n][r] + bb;
        if (EPI==0){
          ((bf16*)outp)[(size_t)row*N + col] = __float2bfloat16(vv);
        } else if (EPI==1){
          float gl = 0.5f*vv*(1.0f + erff(vv*0.70710678118654752f));
          ((bf16*)outp)[(size_t)row*N + col] = __float2bfloat16(gl);
        } else {
          ((float*)outp)[(size_t)row*N + col] += vv;
        }
      }
    }
  }
}

// ---------------- 256x256 8-phase GEMM (T2+T3+T4+T5) ----------------
// out[M,N] = A[M,lda] @ Bt[N,ldb]^T (+bias).  BK=64, 8 waves, 128KB LDS ring.
// EPI: 0 = bf16+bias, 1 = exact-GELU bf16+bias, 2 = fp32 atomicAdd (+bias when z==0)
// QKV3: block-uniform 3-way bias select by output column block (N multiple of 1024).
template<int EPI, int QKV3>
__global__ __launch_bounds__(512,2) void gemm8_k(
    const bf16* __restrict__ A, int lda,
    const bf16* __restrict__ Bt, int ldb,
    const float* __restrict__ b0, const float* __restrict__ b1v,
    const float* __restrict__ b2v, int addbias,
    void* __restrict__ outp, int N, int Ksub)
{
  __shared__ char lds[131072];
  char* Ae = lds;             // even A tile [256 rows][128B], halves at +0 / +16384
  char* Be = lds + 32768;
  char* Ao = lds + 65536;
  char* Bo = lds + 98304;

  const int tid = threadIdx.x, lane = tid & 63;
  const int w = tid >> 6, wr = w >> 2, wc = w & 3;
  const int r16 = lane & 15, g = lane >> 4, l7 = lane & 7;

  // bijective XCD swizzle (all grids here have nwg % 8 == 0)
  int bid = blockIdx.y * gridDim.x + blockIdx.x;
  int cpx = (gridDim.x * gridDim.y) >> 3;
  int swz = (bid & 7) * cpx + (bid >> 3);
  int tn = swz % gridDim.x, tm = swz / gridDim.x;
  const int R0 = tm * 256, C0 = tn * 256;
  const int kz = blockIdx.z;
  const bf16* Ab = A  + (size_t)kz * Ksub;
  const bf16* Bb = Bt + (size_t)kz * Ksub;
  const int KT = Ksub >> 6;   // number of BK=64 tiles; must be even, >= 2

  // stage one half-tile (128 rows x 64 cols) with source-side XOR swizzle
  auto stage = [&](char* slot, const bf16* src, int ld, int row0, int tile){
    int ut = tile < KT ? tile : KT-1;   // clamp keeps vmcnt accounting uniform
    #pragma unroll
    for (int i=0;i<2;i++){
      int f = i*512 + tid;
      int r = f >> 3, c = f & 7;
      int cg = c ^ (r & 7);
      gload16(src + (size_t)(row0 + r)*ld + ut*64 + cg*8, slot + f*16);
    }
  };

  // prologue: even <- tile0 (all 4 halves), odd.A0/B0 <- tile1
  stage(Ae,       Ab, lda, R0,     0);
  stage(Be,       Bb, ldb, C0,     0);
  stage(Ae+16384, Ab, lda, R0+128, 0);
  stage(Be+16384, Bb, ldb, C0+128, 0);
  stage(Ao,       Ab, lda, R0,     1);
  stage(Bo,       Bb, ldb, C0,     1);
  asm volatile("s_waitcnt vmcnt(8)" ::: "memory");
  __builtin_amdgcn_s_barrier();

  const f32x4 fz = {0.f,0.f,0.f,0.f};
  f32x4 acc[8][4];
  #pragma unroll
  for (int m=0;m<8;m++){
    #pragma unroll
    for (int n=0;n<4;n++) acc[m][n] = fz;
  }

  // phase: ds-read 12 frags -> stage 1 half-tile -> MFMA x16 -> vmcnt(8)+barrier.
  // A rows of phase (mh,*): mh*128 + wr*64 + m*16 ; B rows: nh*128 + wc*32 + n*16
  // (quadrant == half, so slots die mid-group; uniform vmcnt(8) proven per-phase)
#define PHASE(mh, nh, Asl, Bsl, SSLOT, SSRC, SLD, SROW, STILE) { \
    short8 af[4][2], bfr[2][2]; \
    _Pragma("unroll") \
    for (int m=0;m<4;m++){ \
      int row = (mh)*128 + wr*64 + m*16 + r16; \
      _Pragma("unroll") \
      for (int k=0;k<2;k++){ int cl = (k*4+g) ^ l7; \
        af[m][k] = *reinterpret_cast<const short8*>((Asl) + row*128 + cl*16); } } \
    _Pragma("unroll") \
    for (int n=0;n<2;n++){ \
      int row = (nh)*128 + wc*32 + n*16 + r16; \
      _Pragma("unroll") \
      for (int k=0;k<2;k++){ int cl = (k*4+g) ^ l7; \
        bfr[n][k] = *reinterpret_cast<const short8*>((Bsl) + row*128 + cl*16); } } \
    stage(SSLOT, SSRC, SLD, SROW, STILE); \
    __builtin_amdgcn_s_setprio(1); \
    _Pragma("unroll") \
    for (int m=0;m<4;m++){ \
      _Pragma("unroll") \
      for (int n=0;n<2;n++){ \
        _Pragma("unroll") \
        for (int k=0;k<2;k++) \
          acc[(mh)*4+m][(nh)*2+n] = __builtin_amdgcn_mfma_f32_16x16x32_bf16( \
              af[m][k], bfr[n][k], acc[(mh)*4+m][(nh)*2+n], 0,0,0); } } \
    __builtin_amdgcn_s_setprio(0); \
    asm volatile("s_waitcnt vmcnt(8)" ::: "memory"); \
    __builtin_amdgcn_s_barrier(); \
  }

  for (int it=0; it<KT/2; ++it){
    int u = 2*it;
    PHASE(0,0, Ae, Be, Ao+16384, Ab, lda, R0+128, u+1)   // stage odd.A1  <- u+1
    PHASE(1,0, Ae, Be, Bo+16384, Bb, ldb, C0+128, u+1)   // stage odd.B1  <- u+1
    PHASE(0,1, Ae, Be, Be,       Bb, ldb, C0,     u+2)   // stage even.B0 <- u+2
    PHASE(1,1, Ae, Be, Ae,       Ab, lda, R0,     u+2)   // stage even.A0 <- u+2
    PHASE(0,0, Ao, Bo, Ae+16384, Ab, lda, R0+128, u+2)   // stage even.A1 <- u+2
    PHASE(1,0, Ao, Bo, Be+16384, Bb, ldb, C0+128, u+2)   // stage even.B1 <- u+2
    PHASE(0,1, Ao, Bo, Bo,       Bb, ldb, C0,     u+3)   // stage odd.B0  <- u+3
    PHASE(1,1, Ao, Bo, Ao,       Ab, lda, R0,     u+3)   // stage odd.A0  <- u+3
  }
#undef PHASE

  // epilogue
  int sel = C0 >> 10;
  const float* bp = QKV3 ? (sel==0 ? b0 : (sel==1 ? b1v : b2v)) : b0;
  int cb0 = QKV3 ? (C0 & 1023) : C0;
  int ab = addbias && (kz == 0);
  #pragma unroll
  for (int mh=0; mh<2; mh++){
    #pragma unroll
    for (int m=0;m<4;m++){
      #pragma unroll
      for (int nh=0; nh<2; nh++){
        #pragma unroll
        for (int n=0;n<2;n++){
          int colrel = nh*128 + wc*32 + n*16 + r16;
          int col = C0 + colrel;
          float bb = ab ? bp[cb0 + colrel] : 0.f;
          #pragma unroll
          for (int r=0;r<4;r++){
            int row = R0 + mh*128 + wr*64 + m*16 + g*4 + r;
            float vv = acc[mh*4+m][nh*2+n][r] + bb;
            if (EPI==0){
              ((bf16*)outp)[(size_t)row*N + col] = __float2bfloat16(vv);
            } else if (EPI==1){
              float gl = 0.5f*vv*(1.0f + erff(vv*0.70710678118654752f));
              ((bf16*)outp)[(size_t)row*N + col] = __float2bfloat16(gl);
            } else {
              atomicAdd((float*)outp + (size_t)row*N + col, vv);
            }
          }
        }
      }
    }
  }
}

// ---------------- Flash attention, non-causal, per (b,h); K,V fully in LDS ----------------
// q,k,v read from fused qkv buffer [M, 3C]: q at col 0, k at 1024, v at 2048.
__global__ __launch_bounds__(512) void attn_k(const bf16* __restrict__ qkv,
    bf16* __restrict__ y)
{
  __shared__ bf16 Ks[T_*64];   // 64 KB, XOR-swizzled rows
  __shared__ bf16 Vs[T_*64];   // 64 KB, shifted-slot rows
  const int SQ = 3*C_;
  int tid = threadIdx.x, lane = tid&63, w = tid>>6;
  int b = blockIdx.z, h = blockIdx.y, qt = blockIdx.x;
  size_t baseQ = ((size_t)b*T_)*SQ + (size_t)h*64;
  size_t baseK = baseQ + 1024;
  size_t baseV = baseQ + 2048;
  size_t baseY = ((size_t)b*T_)*C_ + (size_t)h*64;

  #pragma unroll
  for (int i=0;i<8;i++){
    int cc = i*512 + tid;
    int row = cc>>3, ch = cc&7;
    short8 kv = *reinterpret_cast<const short8*>(qkv + baseK + (size_t)row*SQ + ch*8);
    short8 vv = *reinterpret_cast<const short8*>(qkv + baseV + (size_t)row*SQ + ch*8);
    int mk = (row&7) ^ (((row>>3)&3)<<1);
    int slotK = ch ^ mk;
    int slotV = (ch + 2*((row>>3)&3)) & 7;
    *reinterpret_cast<short8*>((char*)Ks + row*128 + slotK*16) = kv;
    *reinterpret_cast<short8*>((char*)Vs + row*128 + slotV*16) = vv;
  }
  __syncthreads();

  int g = lane>>4, r16 = lane&15;
  int qrow0 = qt*256 + w*32;
  short8 qf[2][2];
  #pragma unroll
  for (int s=0;s<2;s++)
    #pragma unroll
    for (int c=0;c<2;c++)
      qf[s][c] = *reinterpret_cast<const short8*>(qkv + baseQ + (size_t)(qrow0 + s*16 + r16)*SQ + c*32 + g*8);

  const f32x4 fz = {0.f,0.f,0.f,0.f};
  float mreg[2] = {-1e30f, -1e30f};
  float lsum[2] = {0.f, 0.f};
  f32x4 yacc[2][4];
  #pragma unroll
  for (int s=0;s<2;s++)
    #pragma unroll
    for (int dt=0;dt<4;dt++) yacc[s][dt] = fz;

  const float SC = 0.18033688011112043f; // (1/sqrt(64)) * log2(e)
  int rl0 = ((r16>>2)<<3) + (r16&3);     // k-row permutation so PV B-frag is lane-local

  for (int kt=0; kt<16; ++kt){
    int rowA = kt*32 + rl0;
    int rowB = rowA + 4;
    short8 kf0[2], kf1[2];
    #pragma unroll
    for (int c=0;c<2;c++){
      int slot = c*4 + g;
      int mkA = (rowA&7) ^ (((rowA>>3)&3)<<1);
      int mkB = (rowB&7) ^ (((rowB>>3)&3)<<1);
      kf0[c] = *reinterpret_cast<const short8*>((char*)Ks + rowA*128 + (slot^mkA)*16);
      kf1[c] = *reinterpret_cast<const short8*>((char*)Ks + rowB*128 + (slot^mkB)*16);
    }
    short8 vf[4];
    #pragma unroll
    for (int dt=0; dt<4; dt++){
      #pragma unroll
      for (int j=0;j<8;j++){
        int row = kt*32 + g*8 + j;
        int col = dt*16 + r16;
        int slot = ((col>>3) + 2*((row>>3)&3)) & 7;
        vf[dt][j] = *reinterpret_cast<const short*>((char*)Vs + row*128 + slot*16 + (col&7)*2);
      }
    }
    short8 pf[2];
    #pragma unroll
    for (int s=0;s<2;s++){
      f32x4 st0 = fz, st1 = fz;
      st0 = __builtin_amdgcn_mfma_f32_16x16x32_bf16(kf0[0], qf[s][0], st0, 0,0,0);
      st0 = __builtin_amdgcn_mfma_f32_16x16x32_bf16(kf0[1], qf[s][1], st0, 0,0,0);
      st1 = __builtin_amdgcn_mfma_f32_16x16x32_bf16(kf1[0], qf[s][0], st1, 0,0,0);
      st1 = __builtin_amdgcn_mfma_f32_16x16x32_bf16(kf1[1], qf[s][1], st1, 0,0,0);
      float p0[4], p1[4];
      float tm = -1e30f;
      #pragma unroll
      for (int r=0;r<4;r++){
        p0[r] = st0[r]*SC; p1[r] = st1[r]*SC;
        tm = fmaxf(tm, fmaxf(p0[r], p1[r]));
      }
      tm = fmaxf(tm, __shfl_xor(tm, 16));
      tm = fmaxf(tm, __shfl_xor(tm, 32));
      float nm = fmaxf(mreg[s], tm);
      float f = exp2f(mreg[s] - nm);
      mreg[s] = nm;
      float psum = 0.f;
      #pragma unroll
      for (int r=0;r<4;r++){
        p0[r] = exp2f(p0[r]-nm); p1[r] = exp2f(p1[r]-nm);
        psum += p0[r] + p1[r];
      }
      lsum[s] = lsum[s]*f + psum;
      #pragma unroll
      for (int dt=0;dt<4;dt++) yacc[s][dt] *= f;
      short8 pp;
      pp[0]=f2bs(p0[0]); pp[1]=f2bs(p0[1]); pp[2]=f2bs(p0[2]); pp[3]=f2bs(p0[3]);
      pp[4]=f2bs(p1[0]); pp[5]=f2bs(p1[1]); pp[6]=f2bs(p1[2]); pp[7]=f2bs(p1[3]);
      pf[s] = pp;
    }
    #pragma unroll
    for (int dt=0;dt<4;dt++){
      yacc[0][dt] = __builtin_amdgcn_mfma_f32_16x16x32_bf16(vf[dt], pf[0], yacc[0][dt], 0,0,0);
      yacc[1][dt] = __builtin_amdgcn_mfma_f32_16x16x32_bf16(vf[dt], pf[1], yacc[1][dt], 0,0,0);
    }
  }

  #pragma unroll
  for (int s=0;s<2;s++){
    float ls = lsum[s];
    ls += __shfl_xor(ls, 16);
    ls += __shfl_xor(ls, 32);
    float inv = 1.0f/ls;
    int qrow = qrow0 + s*16 + r16;
    #pragma unroll
    for (int dt=0;dt<4;dt++){
      ushort4 o;
      o.x = (unsigned short)f2bs(yacc[s][dt][0]*inv);
      o.y = (unsigned short)f2bs(yacc[s][dt][1]*inv);
      o.z = (unsigned short)f2bs(yacc[s][dt][2]*inv);
      o.w = (unsigned short)f2bs(yacc[s][dt][3]*inv);
      *reinterpret_cast<ushort4*>(y + baseY + (size_t)qrow*C_ + dt*16 + g*4) = o;
    }
  }
}

// ---------------- final LN (last token only) + pooling head ----------------
__global__ __launch_bounds__(256) void head_k(const float* __restrict__ hbuf,
    const float* __restrict__ gf, const float* __restrict__ bfv,
    const float* __restrict__ Wp, const float* __restrict__ bp, float* __restrict__ out)
{
  int b = blockIdx.x, tid = threadIdx.x;
  int w = tid >> 6, lane = tid & 63;
  const float* rowp = hbuf + ((size_t)(b*T_ + T_-1))*C_;
  float4 v = reinterpret_cast<const float4*>(rowp)[tid];
  float s = v.x+v.y+v.z+v.w;
  float ss = v.x*v.x+v.y*v.y+v.z*v.z+v.w*v.w;
  #pragma unroll
  for (int o=32;o>=1;o>>=1){ s += __shfl_xor(s,o); ss += __shfl_xor(ss,o); }
  __shared__ float sa[4], sb[4];
  if (lane==0){ sa[w]=s; sb[w]=ss; }
  __syncthreads();
  s  = sa[0]+sa[1]+sa[2]+sa[3];
  ss = sb[0]+sb[1]+sb[2]+sb[3];
  float mean = s * (1.0f/C_);
  float var  = ss * (1.0f/C_) - mean*mean;
  float rs = rsqrtf(var + 1e-5f);
  __shared__ float nrm[C_];
  float4 gv = reinterpret_cast<const float4*>(gf)[tid];
  float4 bv = reinterpret_cast<const float4*>(bfv)[tid];
  nrm[tid*4+0] = (v.x-mean)*rs*gv.x + bv.x;
  nrm[tid*4+1] = (v.y-mean)*rs*gv.y + bv.y;
  nrm[tid*4+2] = (v.z-mean)*rs*gv.z + bv.z;
  nrm[tid*4+3] = (v.w-mean)*rs*gv.w + bv.w;
  __syncthreads();
  float acc = bp[tid];
  #pragma unroll 4
  for (int kk=0; kk<C_; kk++) acc += nrm[kk]*Wp[(size_t)kk*256 + tid];
  out[b*256 + tid] = acc;
}

extern "C" void kernel_launch(void* const* d_in, const int* in_sizes, int n_in,
                              void* d_out, int out_size, void* d_ws, size_t ws_size,
                              hipStream_t stream)
{
  const float* x  = (const float*)d_in[0];
  const float* Wq = (const float*)d_in[1];
  const float* bq = (const float*)d_in[2];
  const float* Wk = (const float*)d_in[3];
  const float* bk = (const float*)d_in[4];
  const float* Wv = (const float*)d_in[5];
  const float* bv = (const float*)d_in[6];
  const float* Wo = (const float*)d_in[7];
  const float* bo = (const float*)d_in[8];
  const float* g1 = (const float*)d_in[9];
  const float* be1= (const float*)d_in[10];
  const float* g2 = (const float*)d_in[11];
  const float* be2= (const float*)d_in[12];
  const float* W1 = (const float*)d_in[13];
  const float* b1 = (const float*)d_in[14];
  const float* W2 = (const float*)d_in[15];
  const float* b2 = (const float*)d_in[16];
  const float* gf = (const float*)d_in[17];
  const float* bfv= (const float*)d_in[18];
  const float* Wp = (const float*)d_in[19];
  const float* bp = (const float*)d_in[20];
  float* out = (float*)d_out;

  const size_t NEED = 209715200;
  if (ws_size < NEED) return;

  char* ws = (char*)d_ws;
  float* hbuf = (float*)ws;                      // 33,554,432 B (fp32 residual)
  bf16* abuf  = (bf16*)(ws + 33554432);          // 16,777,216 B
  bf16* qkv   = (bf16*)(ws + 50331648);          // 50,331,648 B  [M, 3C] fused q|k|v
  bf16* ybuf  = (bf16*)(ws + 100663296);         // 16,777,216 B
  bf16* mid   = (bf16*)(ws + 117440512);         // 67,108,864 B
  bf16* slab  = (bf16*)(ws + 184549376);         // 25,165,824 B (per-layer bf16 weights, transposed)

  hipMemcpyAsync(hbuf, x, (size_t)M_*C_*sizeof(float), hipMemcpyDeviceToDevice, stream);

  dim3 gN1024(8, 64);
  for (int l=0; l<L_; ++l){
    size_t oCC = (size_t)l*C_*C_, oC = (size_t)l*C_;
    size_t oCF = (size_t)l*C_*F_, oF = (size_t)l*F_;
    convert_w<<<12288, 256, 0, stream>>>(Wq+oCC, Wk+oCC, Wv+oCC, Wo+oCC, W1+oCF, W2+oCF, slab);
    ln_k<<<M_, 256, 0, stream>>>(hbuf, g1+oC, be1+oC, abuf);
    // fused QKV: [8192,1024] @ [3072,1024]^T -> [8192,3072]
    gemm8_k<0,1><<<dim3(12,32), 512, 0, stream>>>(abuf, C_, slab, C_,
        bq+oC, bk+oC, bv+oC, 1, qkv, 3*C_, C_);
    attn_k<<<dim3(2, H_, B_), 512, 0, stream>>>(qkv, ybuf);
    gemm_k<2><<<gN1024, 256, 0, stream>>>(ybuf, slab + (size_t)3*C_*C_, bo+oC, hbuf, C_, C_);
    ln_k<<<M_, 256, 0, stream>>>(hbuf, g2+oC, be2+oC, abuf);
    // W1: [8192,1024] @ [4096,1024]^T -> GELU -> [8192,4096]
    gemm8_k<1,0><<<dim3(16,32), 512, 0, stream>>>(abuf, C_, slab + (size_t)4*C_*C_, C_,
        b1+oF, b1+oF, b1+oF, 1, mid, F_, C_);
    // W2: split-K=2, fp32 atomic accumulate into residual
    gemm8_k<2,0><<<dim3(4,32,2), 512, 0, stream>>>(mid, F_, slab + (size_t)4*C_*C_ + (size_t)C_*F_, F_,
        b2+oC, b2+oC, b2+oC, 1, hbuf, C_, F_/2);
  }
  head_k<<<B_, 256, 0, stream>>>(hbuf, gf, bfv, Wp, bp, out);
}